// Round 1
// baseline (117.061 us; speedup 1.0000x reference)
//
#include <hip/hip_runtime.h>

#define NN 512
#define DD 128
#define MARGIN_F 0.3f

// Kernel 1: pairwise Euclidean distances d[i][j] = ||x_i - x_j||.
// One block per row i; 256 threads each cover 2 columns j.
// Also zero-inits the sum/count accumulators (ws is poisoned 0xAA).
__global__ __launch_bounds__(256) void dist_kernel(const float* __restrict__ x,
                                                   float* __restrict__ dmat,
                                                   float* __restrict__ sum_out,
                                                   unsigned int* __restrict__ cnt_out) {
    if (blockIdx.x == 0 && threadIdx.x == 0) { *sum_out = 0.0f; *cnt_out = 0u; }
    __shared__ float xi[DD];
    const int i = blockIdx.x;
    if (threadIdx.x < DD) xi[threadIdx.x] = x[i * DD + threadIdx.x];
    __syncthreads();
    for (int j = threadIdx.x; j < NN; j += blockDim.x) {
        const float4* xj = (const float4*)(x + j * DD);
        float acc = 0.0f;
#pragma unroll
        for (int c = 0; c < DD / 4; ++c) {
            float4 v = xj[c];
            float a0 = xi[4 * c + 0] - v.x;
            float a1 = xi[4 * c + 1] - v.y;
            float a2 = xi[4 * c + 2] - v.z;
            float a3 = xi[4 * c + 3] - v.w;
            acc = fmaf(a0, a0, acc);
            acc = fmaf(a1, a1, acc);
            acc = fmaf(a2, a2, acc);
            acc = fmaf(a3, a3, acc);
        }
        dmat[i * NN + j] = sqrtf(acc);  // acc >= 0 by construction
    }
}

// Kernel 2: per-anchor masked triplet reduction.
// mask == (labels[j]==labels[i] && j!=i && labels[k]!=labels[i]);
// the j!=k and i!=k distinctness conditions follow from the label conditions.
__global__ __launch_bounds__(256) void triplet_kernel(const float* __restrict__ dmat,
                                                      const int* __restrict__ labels,
                                                      float* __restrict__ sum_out,
                                                      unsigned int* __restrict__ cnt_out) {
    const int i = blockIdx.x;
    __shared__ float ds[NN];
    __shared__ int ls[NN];
    __shared__ float wsum[4];
    __shared__ unsigned int wcnt[4];
    for (int j = threadIdx.x; j < NN; j += blockDim.x) {
        ds[j] = dmat[i * NN + j];
        ls[j] = labels[j];
    }
    __syncthreads();
    const int li = ls[i];
    float lsum = 0.0f;
    unsigned int lcnt = 0u;
    for (int j = 0; j < NN; ++j) {
        // uniform across the block -> cheap scalar branch, no divergence
        if (ls[j] != li || j == i) continue;
        const float dij = ds[j] + MARGIN_F;
        for (int k = threadIdx.x; k < NN; k += blockDim.x) {
            if (ls[k] == li) continue;  // excludes k==i too
            float v = dij - ds[k];
            lsum += fmaxf(v, 0.0f);
            if (v > 1e-16f) lcnt++;
        }
    }
    // wave (64-lane) reduction, then cross-wave via LDS
    for (int off = 32; off > 0; off >>= 1) {
        lsum += __shfl_down(lsum, off);
        lcnt += __shfl_down(lcnt, off);
    }
    const int wave = threadIdx.x >> 6;
    const int lane = threadIdx.x & 63;
    if (lane == 0) { wsum[wave] = lsum; wcnt[wave] = lcnt; }
    __syncthreads();
    if (threadIdx.x == 0) {
        float bs = wsum[0] + wsum[1] + wsum[2] + wsum[3];
        unsigned int bc = wcnt[0] + wcnt[1] + wcnt[2] + wcnt[3];
        atomicAdd(sum_out, bs);
        atomicAdd(cnt_out, bc);
    }
}

// Kernel 3: loss = sum / (num_pos + eps)
__global__ void finalize_kernel(const float* __restrict__ sum_out,
                                const unsigned int* __restrict__ cnt_out,
                                float* __restrict__ out) {
    out[0] = sum_out[0] / ((float)cnt_out[0] + 1e-16f);
}

extern "C" void kernel_launch(void* const* d_in, const int* in_sizes, int n_in,
                              void* d_out, int out_size, void* d_ws, size_t ws_size,
                              hipStream_t stream) {
    const float* x = (const float*)d_in[0];        // [512,128] fp32
    const int* labels = (const int*)d_in[1];       // [512] int32
    float* out = (float*)d_out;                    // scalar fp32

    float* dmat = (float*)d_ws;                    // 512*512 fp32 = 1 MB
    float* sum_out = dmat + NN * NN;
    unsigned int* cnt_out = (unsigned int*)(sum_out + 1);

    dist_kernel<<<NN, 256, 0, stream>>>(x, dmat, sum_out, cnt_out);
    triplet_kernel<<<NN, 256, 0, stream>>>(dmat, labels, sum_out, cnt_out);
    finalize_kernel<<<1, 1, 0, stream>>>(sum_out, cnt_out, out);
}

// Round 2
// 90.858 us; speedup vs baseline: 1.2884x; 1.2884x over previous
//
#include <hip/hip_runtime.h>

#define NN 512
#define DD 128
#define MARGIN_F 0.3f

// Fully fused: block i computes distance row d[i][*] from x (L2-resident,
// 256 KB), compacts positives (same label, j!=i) into an LDS list during the
// distance pass, then reduces relu(d_ij + margin - d_ik) over negatives k.
// Last block (ticket) computes the final scalar. No dmat in global memory,
// single kernel launch.
__global__ __launch_bounds__(256) void fused_triplet_kernel(
    const float* __restrict__ x,
    const int* __restrict__ labels,
    float* __restrict__ out,
    float* __restrict__ sum_out,
    unsigned int* __restrict__ cnt_out,
    unsigned int* __restrict__ ticket) {

    const int i = blockIdx.x;
    const int tid = threadIdx.x;

    __shared__ float xi[DD];
    __shared__ float ds[NN];
    __shared__ int ls[NN];
    __shared__ float tvals[NN];   // d_ij + margin for each positive j (compacted)
    __shared__ int npos;
    __shared__ float wsum[4];
    __shared__ unsigned int wcnt[4];

    if (tid < DD) xi[tid] = x[i * DD + tid];
    if (tid == 0) npos = 0;
    for (int j = tid; j < NN; j += 256) ls[j] = labels[j];
    __syncthreads();

    const int li = ls[i];

    // Distance row + positive compaction. Thread t handles j = t, t+256.
    for (int j = tid; j < NN; j += 256) {
        const float4* xj = (const float4*)(x + j * DD);
        float acc = 0.0f;
#pragma unroll
        for (int c = 0; c < DD / 4; ++c) {
            float4 v = xj[c];
            float4 u = ((const float4*)xi)[c];   // LDS broadcast read
            float a0 = u.x - v.x;
            float a1 = u.y - v.y;
            float a2 = u.z - v.z;
            float a3 = u.w - v.w;
            acc = fmaf(a0, a0, acc);
            acc = fmaf(a1, a1, acc);
            acc = fmaf(a2, a2, acc);
            acc = fmaf(a3, a3, acc);
        }
        float dj = sqrtf(acc);
        ds[j] = dj;
        if (ls[j] == li && j != i) {
            int p = atomicAdd(&npos, 1);       // LDS atomic, ~10 per block
            tvals[p] = dj + MARGIN_F;
        }
    }
    __syncthreads();

    // Triplet reduction: each thread owns k = tid, tid+256; loop positives.
    const int np = npos;
    float lsum = 0.0f;
    unsigned int lcnt = 0u;
    for (int k = tid; k < NN; k += 256) {
        if (ls[k] == li) continue;             // excludes k==i too
        const float dk = ds[k];
        for (int p = 0; p < np; ++p) {
            float v = tvals[p] - dk;
            lsum += fmaxf(v, 0.0f);
            if (v > 1e-16f) lcnt++;
        }
    }

    // Wave (64) shuffle reduction, then cross-wave via LDS.
    for (int off = 32; off > 0; off >>= 1) {
        lsum += __shfl_down(lsum, off);
        lcnt += __shfl_down(lcnt, off);
    }
    const int wave = tid >> 6;
    const int lane = tid & 63;
    if (lane == 0) { wsum[wave] = lsum; wcnt[wave] = lcnt; }
    __syncthreads();

    if (tid == 0) {
        float bs = wsum[0] + wsum[1] + wsum[2] + wsum[3];
        unsigned int bc = wcnt[0] + wcnt[1] + wcnt[2] + wcnt[3];
        atomicAdd(sum_out, bs);
        atomicAdd(cnt_out, bc);
        __threadfence();                        // adds visible before ticket
        unsigned int old = atomicAdd(ticket, 1u);
        if (old == gridDim.x - 1) {             // last block finalizes
            float total = atomicAdd(sum_out, 0.0f);        // atomic read
            unsigned int tc = atomicAdd(cnt_out, 0u);
            out[0] = total / ((float)tc + 1e-16f);
        }
    }
}

extern "C" void kernel_launch(void* const* d_in, const int* in_sizes, int n_in,
                              void* d_out, int out_size, void* d_ws, size_t ws_size,
                              hipStream_t stream) {
    const float* x = (const float*)d_in[0];     // [512,128] fp32
    const int* labels = (const int*)d_in[1];    // [512] int32
    float* out = (float*)d_out;                 // scalar fp32

    float* sum_out = (float*)d_ws;
    unsigned int* cnt_out = (unsigned int*)d_ws + 1;
    unsigned int* ticket = (unsigned int*)d_ws + 2;

    // ws is re-poisoned to 0xAA before every timed launch; zero the 12 bytes
    // of accumulators (async memset is graph-capture safe).
    hipMemsetAsync(d_ws, 0, 12, stream);
    fused_triplet_kernel<<<NN, 256, 0, stream>>>(x, labels, out, sum_out,
                                                 cnt_out, ticket);
}

// Round 3
// 71.604 us; speedup vs baseline: 1.6349x; 1.2689x over previous
//
#include <hip/hip_runtime.h>

#define NN 512
#define DD 128
#define MARGIN_F 0.3f

// Kernel 1: block i computes distance row d[i][*] from x (L2-resident,
// 256 KB), compacts positives (same label, j!=i) into an LDS list, reduces
// relu(d_ij + margin - d_ik) over negatives k, and writes ONE partial
// sum/count per block to ws (unconditional store -> no zero-init, no
// memset node, no device atomics).
__global__ __launch_bounds__(512) void triplet_partial_kernel(
    const float* __restrict__ x,
    const int* __restrict__ labels,
    float* __restrict__ psum,
    unsigned int* __restrict__ pcnt) {

    const int i = blockIdx.x;
    const int tid = threadIdx.x;   // one j (and one k) per thread

    __shared__ float xi[DD];
    __shared__ float ds[NN];
    __shared__ int ls[NN];
    __shared__ float tvals[NN];    // d_ij + margin for each positive j
    __shared__ int npos;
    __shared__ float wsum[8];
    __shared__ unsigned int wcnt[8];

    if (tid < DD) xi[tid] = x[i * DD + tid];
    if (tid == 0) npos = 0;
    ls[tid] = labels[tid];
    __syncthreads();

    const int li = ls[i];

    // Distance row + positive compaction (j == tid).
    {
        const float4* xj = (const float4*)(x + tid * DD);
        float acc = 0.0f;
#pragma unroll
        for (int c = 0; c < DD / 4; ++c) {
            float4 v = xj[c];
            float4 u = ((const float4*)xi)[c];   // LDS broadcast read
            float a0 = u.x - v.x;
            float a1 = u.y - v.y;
            float a2 = u.z - v.z;
            float a3 = u.w - v.w;
            acc = fmaf(a0, a0, acc);
            acc = fmaf(a1, a1, acc);
            acc = fmaf(a2, a2, acc);
            acc = fmaf(a3, a3, acc);
        }
        float dj = sqrtf(acc);
        ds[tid] = dj;
        if (ls[tid] == li && tid != i) {
            int p = atomicAdd(&npos, 1);         // LDS atomic, ~10 per block
            tvals[p] = dj + MARGIN_F;
        }
    }
    __syncthreads();

    // Triplet reduction: thread tid owns k == tid.
    const int np = npos;
    float lsum = 0.0f;
    unsigned int lcnt = 0u;
    if (ls[tid] != li) {                         // negative k (excludes k==i)
        const float dk = ds[tid];
        for (int p = 0; p < np; ++p) {
            float v = tvals[p] - dk;
            lsum += fmaxf(v, 0.0f);
            lcnt += (v > 1e-16f) ? 1u : 0u;
        }
    }

    // Wave (64) shuffle reduction, then cross-wave via LDS (8 waves).
    for (int off = 32; off > 0; off >>= 1) {
        lsum += __shfl_down(lsum, off);
        lcnt += __shfl_down(lcnt, off);
    }
    const int wave = tid >> 6;
    const int lane = tid & 63;
    if (lane == 0) { wsum[wave] = lsum; wcnt[wave] = lcnt; }
    __syncthreads();

    if (tid == 0) {
        float bs = 0.0f;
        unsigned int bc = 0u;
#pragma unroll
        for (int w = 0; w < 8; ++w) { bs += wsum[w]; bc += wcnt[w]; }
        psum[i] = bs;                            // plain stores, slot per block
        pcnt[i] = bc;
    }
}

// Kernel 2: reduce 512 partials -> scalar loss. One block, 512 threads.
__global__ __launch_bounds__(512) void reduce_kernel(
    const float* __restrict__ psum,
    const unsigned int* __restrict__ pcnt,
    float* __restrict__ out) {

    const int tid = threadIdx.x;
    __shared__ float wsum[8];
    __shared__ unsigned int wcnt[8];

    float lsum = psum[tid];
    unsigned int lcnt = pcnt[tid];
    for (int off = 32; off > 0; off >>= 1) {
        lsum += __shfl_down(lsum, off);
        lcnt += __shfl_down(lcnt, off);
    }
    const int wave = tid >> 6;
    const int lane = tid & 63;
    if (lane == 0) { wsum[wave] = lsum; wcnt[wave] = lcnt; }
    __syncthreads();
    if (tid == 0) {
        float bs = 0.0f;
        unsigned int bc = 0u;
#pragma unroll
        for (int w = 0; w < 8; ++w) { bs += wsum[w]; bc += wcnt[w]; }
        out[0] = bs / ((float)bc + 1e-16f);
    }
}

extern "C" void kernel_launch(void* const* d_in, const int* in_sizes, int n_in,
                              void* d_out, int out_size, void* d_ws, size_t ws_size,
                              hipStream_t stream) {
    const float* x = (const float*)d_in[0];     // [512,128] fp32
    const int* labels = (const int*)d_in[1];    // [512] int32
    float* out = (float*)d_out;                 // scalar fp32

    float* psum = (float*)d_ws;                 // 512 floats
    unsigned int* pcnt = (unsigned int*)d_ws + NN;  // 512 uints

    triplet_partial_kernel<<<NN, 512, 0, stream>>>(x, labels, psum, pcnt);
    reduce_kernel<<<1, 512, 0, stream>>>(psum, pcnt, out);
}